// Round 4
// baseline (143.704 us; speedup 1.0000x reference)
//
#include <hip/hip_runtime.h>

// ---- problem constants (from reference) ----
constexpr int T_LEN    = 192000;            // samples per signal
constexpr int N_SIG    = 512;               // 16*32 signals per input
constexpr int FRAME    = 9600;              // 0.4 s @ 24 kHz
constexpr int SHIFT    = 2880;              // 70% overlap
constexpr int SUB      = 960;               // gcd(FRAME, SHIFT)
constexpr int NFRAMES  = (T_LEN - FRAME) / SHIFT + 1;   // 64
constexpr int SUB_PER_SHIFT = SHIFT / SUB;  // 3
constexpr int SUB_PER_FRAME = FRAME / SUB;  // 10
constexpr int NSUB     = (NFRAMES - 1) * SUB_PER_SHIFT + SUB_PER_FRAME; // 199
constexpr int F4_PER_SUB = SUB / 4;         // 240 float4 per sub-block
constexpr int NWAVES   = 8;                 // 512 threads/block

typedef float f32x4 __attribute__((ext_vector_type(4)));

__device__ __forceinline__ float wave_reduce_f32(float v) {
    #pragma unroll
    for (int off = 32; off > 0; off >>= 1) v += __shfl_xor(v, off);
    return v;
}

__device__ __forceinline__ double wave_reduce_f64(double v) {
    #pragma unroll
    for (int off = 32; off > 0; off >>= 1) v += __shfl_xor(v, off);
    return v;
}

// Computes LUFS of one signal using the whole block (8 waves).
// Wave w handles sub-blocks w, w+8, ... (nontemporal coalesced float4 loads,
// per-lane square-accumulate, wave tree-reduce -> LDS); then wave 0 does the
// gating epilogue in f64 (one frame per lane, NFRAMES==64).
// Return value is valid in all lanes of wave 0 (butterfly gives all-lane result).
// Internal barriers also protect s_sub for a subsequent call.
__device__ double block_lufs(const f32x4* __restrict__ sig4,
                             int wave, int lane, float* s_sub)
{
    for (int k = wave; k < NSUB; k += NWAVES) {
        float acc = 0.0f;
        const int base = k * F4_PER_SUB;
        #pragma unroll
        for (int i = 0; i < 4; ++i) {
            int idx = i * 64 + lane;
            if (idx < F4_PER_SUB) {
                f32x4 v = __builtin_nontemporal_load(&sig4[base + idx]);
                acc += v.x * v.x + v.y * v.y + v.z * v.z + v.w * v.w;
            }
        }
        acc = wave_reduce_f32(acc);
        if (lane == 0) s_sub[k] = acc;
    }
    __syncthreads();

    double lufs = 0.0;
    if (wave == 0) {
        float zs = 0.0f;
        const int b0 = lane * SUB_PER_SHIFT;
        #pragma unroll
        for (int j = 0; j < SUB_PER_FRAME; ++j) zs += s_sub[b0 + j];
        const double z  = (double)zs / (double)FRAME;   // mean-square energy
        const double el = -0.691 + 10.0 * log10(z + 1e-8);

        // absolute gating
        const double ia = (el > -70.0) ? 1.0 : 0.0;
        double sz = wave_reduce_f64(z * ia);
        double si = wave_reduce_f64(ia);
        const double z_ave_a = sz / (si + 1e-8);

        // relative gating: 10 dB below absolute-gated loudness
        const double gamma_r = -0.691 + 10.0 * log10(z_ave_a + 1e-8) - 10.0;
        const double iar = ia * ((el > gamma_r) ? 1.0 : 0.0);
        double sz2 = wave_reduce_f64(z * iar);
        double si2 = wave_reduce_f64(iar);
        const double z_ave_ar = sz2 / (si2 + 1e-8);

        lufs = -0.691 + 10.0 * log10(z_ave_ar + 1e-8);
    }
    __syncthreads();   // s_sub may be overwritten by the caller's next pass
    return lufs;
}

// One block per signal n: lufs(x[n]), lufs(y[n]), hinge -> d_ws; last block
// to arrive does the fixed-order final reduction (bit-deterministic) -> d_out.
__global__ __launch_bounds__(512) void dhaspi_fused_kernel(
    const float* __restrict__ x, const float* __restrict__ y,
    double* __restrict__ hinge_ws,         // [N_SIG]
    unsigned int* __restrict__ cnt,        // [1], zeroed per call by memset node
    float* __restrict__ out)
{
    const int n    = blockIdx.x;
    const int tid  = threadIdx.x;
    const int wave = tid >> 6;
    const int lane = tid & 63;

    __shared__ float s_sub[NSUB];
    __shared__ bool  s_win;

    const f32x4* x4 = reinterpret_cast<const f32x4*>(x + (size_t)n * T_LEN);
    const f32x4* y4 = reinterpret_cast<const f32x4*>(y + (size_t)n * T_LEN);

    const double lx = block_lufs(x4, wave, lane, s_sub);
    const double ly = block_lufs(y4, wave, lane, s_sub);

    if (tid == 0) {
        double h = ly - lx;
        h = (h > 0.0) ? h : 0.0;
        // agent-scope store so the winner (possibly another XCD) sees it
        __hip_atomic_store(&hinge_ws[n], h, __ATOMIC_RELAXED,
                           __HIP_MEMORY_SCOPE_AGENT);
        // acq_rel ticket: release our hinge store, acquire everyone else's
        unsigned int old = __hip_atomic_fetch_add(cnt, 1u, __ATOMIC_ACQ_REL,
                                                  __HIP_MEMORY_SCOPE_AGENT);
        s_win = (old == (unsigned int)(gridDim.x - 1));
    }
    __syncthreads();

    if (s_win) {
        // fixed-order (index-order) reduction: bit-exact across replays
        double v = __hip_atomic_load(&hinge_ws[tid], __ATOMIC_RELAXED,
                                     __HIP_MEMORY_SCOPE_AGENT);
        v = wave_reduce_f64(v);
        __shared__ double sd[NWAVES];
        if (lane == 0) sd[wave] = v;
        __syncthreads();
        if (tid == 0) {
            double t = 0.0;
            #pragma unroll
            for (int i = 0; i < NWAVES; ++i) t += sd[i];
            out[0] = (float)(1e-4 * t);
        }
    }
}

extern "C" void kernel_launch(void* const* d_in, const int* in_sizes, int n_in,
                              void* d_out, int out_size, void* d_ws, size_t ws_size,
                              hipStream_t stream) {
    const float* x = (const float*)d_in[0];
    const float* y = (const float*)d_in[1];
    float* out = (float*)d_out;

    // d_ws layout: [0, 4096) hinge doubles (overwritten every call),
    //              [4096, 4100) ticket counter (must be zero at call start)
    double* hinge_ws = (double*)d_ws;
    unsigned int* cnt = (unsigned int*)((char*)d_ws + N_SIG * sizeof(double));

    hipMemsetAsync(cnt, 0, sizeof(unsigned int), stream);
    dhaspi_fused_kernel<<<N_SIG, 512, 0, stream>>>(x, y, hinge_ws, cnt, out);
}